// Round 4
// baseline (508.341 us; speedup 1.0000x reference)
//
#include <hip/hip_runtime.h>
#include <math.h>

#define NB 32          // batch
#define NN 32          // max gt per image
#define NG (NB*NN)     // total gt records
#define NC 81          // classes
#define RSZ 416.0f

// bce(sigmoid(x), 1) = softplus(-x); bce(sigmoid(x), 0) = softplus(x)
__device__ __forceinline__ float softplusf(float x) {
    return fmaxf(x, 0.f) + log1pf(expf(-fabsf(x)));
}

// -------------------------------------------------------------------------
// Kernel A: per-GT assignment, one thread per (b, n).
// JAX semantics: b_safe = where(assign, b, -1) with mode='drop' — but
// negative indices WRAP before OOB handling, so -1 -> B-1 = 31. Every GT
// scatters at EVERY scale, into image b if assigned there, else image 31.
// Per scale i, writes:
//   meta[i*NG+g]: bits 0-5 cellx | 6-11 celly | 12-13 j | 14-20 cls
//                 | 21-25 eb (effective batch) | 26 valid(gt_mask)
//   rect[(i*NG+g)*4]: {tx, ty, tw, th} at scale i.
// -------------------------------------------------------------------------
__global__ __launch_bounds__(256) void yolo_assign(
    const float* __restrict__ gt_boxes, const int* __restrict__ gt_labels,
    const unsigned* __restrict__ gt_mask,
    const float* __restrict__ aw_l, const float* __restrict__ aw_m,
    const float* __restrict__ aw_s,
    int* __restrict__ meta, float* __restrict__ rect)
{
    int t = blockIdx.x * blockDim.x + threadIdx.x;
    if (t >= NG) return;
    int b = t / NN;

    // gt_mask storage detect: int32 {0,1} vs packed uint8 bools
    bool u8 = false;
    for (int k = 0; k < 256; ++k)
        if (gt_mask[k] & 0xFFFFFF00u) { u8 = true; break; }
    int valid = u8 ? (((const unsigned char*)gt_mask)[t] != 0)
                   : (gt_mask[t] != 0);

    const float* bx = gt_boxes + t * 4;
    float x1 = bx[0], y1 = bx[1], x2 = bx[2], y2 = bx[3];
    float cx0 = (x1 + x2) * 0.5f, cy0 = (y1 + y2) * 0.5f;
    float w0 = x2 - x1, h0 = y2 - y1;

    const float* anch[3] = { aw_l, aw_m, aw_s };
    const int    Ss[3]   = { 13, 26, 52 };

    // ---- pass 1: best scale via exact max-IoU (separable in x/y) --------
    float best_m = -1.f; int best = 0;
    for (int i = 0; i < 3; ++i) {
        int Si = Ss[i]; float S = (float)Si;
        float stride = RSZ / S;
        float cx = cx0 * S, cy = cy0 * S, w = w0 * S, h = h0 * S;
        float gx1 = cx - w * 0.5f, gy1 = cy - h * 0.5f;
        float gx2 = cx + w * 0.5f, gy2 = cy + h * 0.5f;
        float ag = (gx2 - gx1) * (gy2 - gy1);
        float m = 0.f;
        for (int a = 0; a < 3; ++a) {
            float aw = anch[i][a * 2 + 0] / stride;
            float ah = anch[i][a * 2 + 1] / stride;
            float aw2 = aw * 0.5f, ah2 = ah * 0.5f;
            float aa = aw * ah;
            float mox = 0.f, moy = 0.f;
            for (int c = 0; c < Si; ++c) {
                float ac = c + 0.5f;
                mox = fmaxf(mox, fminf(gx2, ac + aw2) - fmaxf(gx1, ac - aw2));
                moy = fmaxf(moy, fminf(gy2, ac + ah2) - fmaxf(gy1, ac - ah2));
            }
            float inter = mox * moy;
            m = fmaxf(m, inter / (ag + aa - inter));
        }
        if (m > best_m) { best_m = m; best = i; }   // first-max wins
    }

    int cls = gt_labels[t] + 1;
    cls = min(max(cls, 0), NC - 1);

    // ---- pass 2: per-scale record (cell, j, targets, effective batch) ---
    for (int i = 0; i < 3; ++i) {
        int Si = Ss[i]; float S = (float)Si;
        float stride = RSZ / S;
        float cx = cx0 * S, cy = cy0 * S, w = w0 * S, h = h0 * S;
        float gx1 = cx - w * 0.5f, gy1 = cy - h * 0.5f;
        float gx2 = cx + w * 0.5f, gy2 = cy + h * 0.5f;
        float ag = (gx2 - gx1) * (gy2 - gy1);

        int cellx = (int)floorf(cx); cellx = min(max(cellx, 0), Si - 1);
        int celly = (int)floorf(cy); celly = min(max(celly, 0), Si - 1);
        float acx = cellx + 0.5f, acy = celly + 0.5f;

        float biou = -1.f; int j = 0;
        for (int a = 0; a < 3; ++a) {
            float aw = anch[i][a * 2 + 0] / stride;
            float ah = anch[i][a * 2 + 1] / stride;
            float ox = fmaxf(0.f, fminf(gx2, acx + aw * 0.5f) - fmaxf(gx1, acx - aw * 0.5f));
            float oy = fmaxf(0.f, fminf(gy2, acy + ah * 0.5f) - fmaxf(gy1, acy - ah * 0.5f));
            float inter = ox * oy;
            float iou = inter / (ag + aw * ah - inter);
            if (iou > biou) { biou = iou; j = a; }  // first-max wins
        }

        float tx = cx - floorf(cx), ty = cy - floorf(cy);
        float awj = anch[i][j * 2 + 0] / stride;
        float ahj = anch[i][j * 2 + 1] / stride;
        float tw = logf(w / awj), th = logf(h / ahj);

        int eb = (valid && best == i) ? b : (NB - 1);  // -1 wraps to B-1
        meta[i * NG + t] = cellx | (celly << 6) | (j << 12) | (cls << 14)
                         | (eb << 21) | (valid ? (1 << 26) : 0);
        float* r = rect + (i * NG + t) * 4;
        r[0] = tx; r[1] = ty; r[2] = tw; r[3] = th;
    }
}

// -------------------------------------------------------------------------
// Kernel B: loss over all cell-anchors of one scale. grid = (blocks, NB).
// Images b<31 match only their own 32 records (eb==b iff assigned);
// image 31 matches ALL 1024 records with eb==31 (wrapped scatters).
// Last match in flat order wins for txy/twh; tcls is the union.
// -------------------------------------------------------------------------
template<int S>
__global__ __launch_bounds__(256) void yolo_loss(
    const float* __restrict__ pred, const float* __restrict__ gt_boxes,
    const float* __restrict__ anch,      // 6 floats, pixel units
    const int* __restrict__ meta, const float* __restrict__ rect,
    int scale, float* __restrict__ out)
{
    constexpr int SS3 = S * S * 3;
    const float stride = RSZ / (float)S;
    int b = blockIdx.y;
    int t = blockIdx.x * 256 + threadIdx.x;

    const int*   ms = meta + scale * NG;
    const float* rs = rect + (size_t)scale * NG * 4;

    __shared__ float s_g[NN][5];     // own gt: gx1,gy1,gx2,gy2,area (grid units)
    __shared__ int   s_valid[NN];
    __shared__ int   s_cm[NG];       // candidate meta (32 or 1024 used)
    __shared__ float s_anch[6];
    __shared__ float s_red[256];

    bool wrapimg = (b == NB - 1);
    int ncand = wrapimg ? NG : NN;
    int cbase = wrapimg ? 0 : b * NN;

    for (int c = threadIdx.x; c < ncand; c += 256) s_cm[c] = ms[cbase + c];
    if (threadIdx.x < NN) {
        int n = threadIdx.x;
        const float* bxp = gt_boxes + (b * NN + n) * 4;
        float x1 = bxp[0], y1 = bxp[1], x2 = bxp[2], y2 = bxp[3];
        float Sf = (float)S;
        float cx = (x1 + x2) * 0.5f * Sf, cy = (y1 + y2) * 0.5f * Sf;
        float w = (x2 - x1) * Sf, h = (y2 - y1) * Sf;
        float gx1 = cx - w * 0.5f, gy1 = cy - h * 0.5f;
        float gx2 = cx + w * 0.5f, gy2 = cy + h * 0.5f;
        s_g[n][0] = gx1; s_g[n][1] = gy1; s_g[n][2] = gx2; s_g[n][3] = gy2;
        s_g[n][4] = (gx2 - gx1) * (gy2 - gy1);
        s_valid[n] = (ms[b * NN + n] >> 26) & 1;
    }
    if (threadIdx.x < 6) s_anch[threadIdx.x] = anch[threadIdx.x];
    __syncthreads();

    float acc = 0.f;
    if (t < SS3) {
        int j  = t % 3;
        int cx = (t / 3) % S;
        int cy = t / (3 * S);
        float aw = s_anch[j * 2 + 0] / stride, ah = s_anch[j * 2 + 1] / stride;
        float acx = cx + 0.5f, acy = cy + 0.5f;
        float ax1 = acx - aw * 0.5f, ax2 = acx + aw * 0.5f;
        float ay1 = acy - ah * 0.5f, ay2 = acy + ah * 0.5f;
        float aa = (ax2 - ax1) * (ay2 - ay1);

        // ignore flag: max IoU vs own image's VALID gts
        float miou = 0.f;
        for (int n = 0; n < NN; ++n) {
            if (!s_valid[n]) continue;
            float ox = fmaxf(0.f, fminf(s_g[n][2], ax2) - fmaxf(s_g[n][0], ax1));
            float oy = fmaxf(0.f, fminf(s_g[n][3], ay2) - fmaxf(s_g[n][1], ay1));
            float inter = ox * oy;
            miou = fmaxf(miou, inter / (s_g[n][4] + aa - inter));
        }

        // scatter matches: last wins for txy/twh, class-union for tcls
        int want = cx | (cy << 6) | (j << 12) | (b << 21);
        const int MASK = 0x3FFF | (31 << 21);
        int win = -1;
        unsigned cb[3] = { 0u, 0u, 0u };
        for (int c = 0; c < ncand; ++c) {
            int m = s_cm[c];
            if ((m & MASK) == want) {
                win = c;
                int cl = (m >> 14) & 127;
                cb[cl >> 5] |= 1u << (cl & 31);
            }
        }

        // pred row: 86 channels, float2-aligned
        const float* p = pred +
            ((size_t)((b * S + cy) * S + cx)) * (3 * (5 + NC)) + j * (5 + NC);
        const float2* p2 = (const float2*)p;
        float2 v2 = p2[2];            // (obj, cls0)
        float pobj = v2.x;

        if (win >= 0) {
            const float* tr = rs + (size_t)(cbase + win) * 4;
            float2 v0 = p2[0], v1 = p2[1];
            float sx = 1.f / (1.f + expf(-v0.x));
            float sy = 1.f / (1.f + expf(-v0.y));
            float dx = sx - tr[0], dy = sy - tr[1];
            float dw = v1.x - tr[2], dh = v1.y - tr[3];
            float xy_l  = 0.5f * (dx * dx + dy * dy);
            float wh_l  = 0.5f * (dw * dw + dh * dh);
            float obj_l = softplusf(-pobj);
            float cls_l = ((cb[0] >> 0) & 1) ? softplusf(-v2.y) : softplusf(v2.y);
            for (int k = 3; k < 43; ++k) {
                float2 v = p2[k];
                int c0 = 2 * k - 5, c1 = 2 * k - 4;
                cls_l += ((cb[c0 >> 5] >> (c0 & 31)) & 1) ? softplusf(-v.x) : softplusf(v.x);
                cls_l += ((cb[c1 >> 5] >> (c1 & 31)) & 1) ? softplusf(-v.y) : softplusf(v.y);
            }
            acc = (5.f * (xy_l + wh_l) + obj_l + cls_l) * (1.f / NB);
        } else {
            float ignore = (miou < 0.5f) ? 1.f : 0.f;
            acc = 0.5f * ignore * softplusf(pobj) * (1.f / NB);
        }
    }

    // block reduction -> one atomic per block
    s_red[threadIdx.x] = acc;
    __syncthreads();
    for (int o = 128; o > 0; o >>= 1) {
        if (threadIdx.x < o) s_red[threadIdx.x] += s_red[threadIdx.x + o];
        __syncthreads();
    }
    if (threadIdx.x == 0) atomicAdd(out, s_red[0]);
}

extern "C" void kernel_launch(void* const* d_in, const int* in_sizes, int n_in,
                              void* d_out, int out_size, void* d_ws, size_t ws_size,
                              hipStream_t stream)
{
    const float*    pred_l    = (const float*)d_in[0];
    const float*    pred_m    = (const float*)d_in[1];
    const float*    pred_s    = (const float*)d_in[2];
    const float*    gt_boxes  = (const float*)d_in[3];
    const int*      gt_labels = (const int*)d_in[4];
    const unsigned* gt_mask   = (const unsigned*)d_in[5];
    const float*    aw_l      = (const float*)d_in[6];
    const float*    aw_m      = (const float*)d_in[7];
    const float*    aw_s      = (const float*)d_in[8];

    int*   meta = (int*)d_ws;                                  // 3*NG ints
    float* rect = (float*)((char*)d_ws + 3 * NG * sizeof(int)); // 3*NG*4 floats

    hipMemsetAsync(d_out, 0, sizeof(float), stream);

    yolo_assign<<<dim3((NG + 255) / 256), 256, 0, stream>>>(
        gt_boxes, gt_labels, gt_mask, aw_l, aw_m, aw_s, meta, rect);

    yolo_loss<13><<<dim3((13 * 13 * 3 + 255) / 256, NB), 256, 0, stream>>>(
        pred_l, gt_boxes, aw_l, meta, rect, 0, (float*)d_out);
    yolo_loss<26><<<dim3((26 * 26 * 3 + 255) / 256, NB), 256, 0, stream>>>(
        pred_m, gt_boxes, aw_m, meta, rect, 1, (float*)d_out);
    yolo_loss<52><<<dim3((52 * 52 * 3 + 255) / 256, NB), 256, 0, stream>>>(
        pred_s, gt_boxes, aw_s, meta, rect, 2, (float*)d_out);
}